// Round 2
// baseline (30847.699 us; speedup 1.0000x reference)
//
#include <hip/hip_runtime.h>
#include <hip/hip_bf16.h>
#include <math.h>

// Tree-LSTM "LogicEncoder": D=10, N=1023 nodes, B=128, LD=256, K=2.
// Round 2: software-pipelined fp32 tiled GEMM (register prefetch + LDS double
// buffer, ONE barrier per K-step), template on rows-per-thread so small levels
// keep the GPU occupied. fp32 kept throughout: measured absmax in fp32 is
// 0.0156 vs 0.02 threshold -> low-precision MFMA paths are numerically unsafe.

#define NNODES 1023
#define BATCH  128
#define LDIM   256

__device__ __forceinline__ float sigmoidf_(float x) {
    return 1.f / (1.f + expf(-x));
}

// ---------------------------------------------------------------------------
// Pack Wbig (768x1024) + bias_big(1024) + Wleaf(256x512) + bias_leaf(512).
__global__ __launch_bounds__(256) void build_weights(
    const float* __restrict__ Wix, const float* __restrict__ bix,
    const float* __restrict__ Wfx, const float* __restrict__ bfx,
    const float* __restrict__ Wux, const float* __restrict__ bux,
    const float* __restrict__ Wi,  const float* __restrict__ bi,
    const float* __restrict__ Wf,  const float* __restrict__ bf,
    const float* __restrict__ Wu,  const float* __restrict__ bu,
    const float* __restrict__ Wcx, const float* __restrict__ bcx,
    const float* __restrict__ Wox, const float* __restrict__ box,
    float* __restrict__ Wbig, float* __restrict__ bias_big,
    float* __restrict__ Wleaf, float* __restrict__ bias_leaf)
{
    int i = blockIdx.x * blockDim.x + threadIdx.x;
    if (i < 768 * 1024) {
        int k = i >> 10, n = i & 1023;
        int g = n >> 8, nn = n & 255;
        float v;
        if (g == 0) {
            v = (k < 256) ? Wix[k * 256 + nn]
              : (k < 512) ? Wi[(k - 256) * 256 + nn]
                          : Wi[65536 + (k - 512) * 256 + nn];
        } else if (g == 1) {
            v = (k < 256) ? Wux[k * 256 + nn]
              : (k < 512) ? Wu[(k - 256) * 256 + nn]
                          : Wu[65536 + (k - 512) * 256 + nn];
        } else {
            int kf = g - 2;  // f0 / f1
            v = (k < 256) ? Wfx[k * 256 + nn]
              : (k < 512) ? Wf[((kf * 2 + 0) * 256 + (k - 256)) * 256 + nn]
                          : Wf[((kf * 2 + 1) * 256 + (k - 512)) * 256 + nn];
        }
        Wbig[i] = v;
        return;
    }
    i -= 768 * 1024;
    if (i < 1024) {
        int g = i >> 8, nn = i & 255;
        float v;
        if (g == 0)      v = bix[nn] + bi[nn] + bi[256 + nn];
        else if (g == 1) v = bux[nn] + bu[nn] + bu[256 + nn];
        else if (g == 2) v = bfx[nn] + bf[nn] + bf[256 + nn];          // bf[0,0]+bf[0,1]
        else             v = bfx[nn] + bf[512 + nn] + bf[768 + nn];    // bf[1,0]+bf[1,1]
        bias_big[i] = v;
        return;
    }
    i -= 1024;
    if (i < 256 * 512) {
        int k = i >> 9, n = i & 511;
        Wleaf[i] = (n < 256) ? Wcx[k * 256 + n] : Wox[k * 256 + (n - 256)];
        return;
    }
    i -= 256 * 512;
    if (i < 512) {
        bias_leaf[i] = (i < 256) ? bcx[i] : box[i - 256];
    }
}

// ---------------------------------------------------------------------------
// Fused GEMM + LSTM epilogue, software-pipelined.
//   RPT:  rows per thread (tile rows R = 16*RPT), 4 cols x NG groups per thread
//   NG:   output column groups (4 = [i|u|f0|f1] internal, 2 = [c|o] leaf)
//   NSEG: K segments of 256 (3 = [x|hL|hR], 1 = x only)
// Tile: R rows x 64 cols x NG groups. Block 256 threads (16 ty x 16 tx).
// Pipeline: prefetch(t+1) -> compute(t) -> ds_write(t+1, other buf) -> barrier.
template<int RPT, int NG, int NSEG>
__global__ __launch_bounds__(256, 4) void gemm_fused(
    const float* __restrict__ x_embed,
    const float* __restrict__ hChild, const float* __restrict__ cChild,
    const float* __restrict__ Wmat, const float* __restrict__ bias,
    float* __restrict__ hOut, float* __restrict__ cOut, int nstart)
{
    constexpr int R    = 16 * RPT;       // rows per tile
    constexpr int K    = NSEG * 256;
    constexpr int NIT  = K / 16;
    constexpr int WLD  = NG * 256;       // leading dim of packed weights
    constexpr int L2NG = (NG == 4) ? 2 : 1;
    __shared__ float As[2][16 * R];
    __shared__ float Bs[2][16 * NG * 64];

    const int tid  = threadIdx.x;
    const int ty   = tid >> 4, tx = tid & 15;
    const int row0 = blockIdx.x * R;
    const int n0   = blockIdx.y * 64;
    const int w    = row0 >> 7;            // node-local index (uniform per block)
    const int ar   = tid % R;              // A-load: row within tile
    const int kq   = (tid / R) * RPT;      // A-load: k offset
    const int b    = (row0 & 127) + ar;    // batch index of that row

    // A source row pointers per K-segment
    const float* spX = x_embed + ((size_t)b * NNODES + (nstart + w)) * LDIM;
    const float* spL = nullptr;
    const float* spR = nullptr;
    if constexpr (NSEG == 3) {
        spL = hChild + ((size_t)(2 * w) * BATCH + b) * LDIM;
        spR = hChild + ((size_t)(2 * w + 1) * BATCH + b) * LDIM;
    }

    float acc[NG][RPT][4];
#pragma unroll
    for (int g = 0; g < NG; ++g)
#pragma unroll
        for (int ii = 0; ii < RPT; ++ii)
#pragma unroll
            for (int jj = 0; jj < 4; ++jj) acc[g][ii][jj] = 0.f;

    float aPre[RPT];
    float4 bPre[NG];

    auto prefetch = [&](int k0) {
        // A: RPT consecutive k-floats of one row
        const float* sp = spX;
        if constexpr (NSEG == 3) {
            int seg = k0 >> 8;
            sp = (seg == 0) ? spX : (seg == 1) ? spL : spR;
        }
        const float* ab = sp + (k0 & 255) + kq;
        if constexpr (RPT == 4) {
            *(float4*)aPre = *(const float4*)ab;
        } else if constexpr (RPT == 1) {
            aPre[0] = *ab;
        } else {  // RPT == 8
            *(float4*)&aPre[0] = *(const float4*)ab;
            *(float4*)&aPre[4] = *(const float4*)(ab + 4);
        }
        // B: NG float4s
#pragma unroll
        for (int q = 0; q < NG; ++q) {
            int F  = q * 256 + tid;              // float4 slot 0..(16*NG*16-1)
            int kk = F >> (4 + L2NG);
            int g  = (F >> 4) & (NG - 1);
            bPre[q] = *(const float4*)(Wmat + (size_t)(k0 + kk) * WLD
                                       + g * 256 + n0 + (tid & 15) * 4);
        }
    };
    auto store = [&](int buf) {
#pragma unroll
        for (int j = 0; j < RPT; ++j)
            As[buf][(kq + j) * R + ar] = aPre[j];
#pragma unroll
        for (int q = 0; q < NG; ++q) {
            int F  = q * 256 + tid;
            int kk = F >> (4 + L2NG);
            int g  = (F >> 4) & (NG - 1);
            *(float4*)&Bs[buf][(kk * NG + g) * 64 + (tid & 15) * 4] = bPre[q];
        }
    };

    // prologue: stage iter 0 into buffer 0
    prefetch(0);
    store(0);
    __syncthreads();

    for (int it = 0; it < NIT; ++it) {
        const int cur = it & 1;
        const bool more = (it + 1 < NIT);
        if (more) prefetch((it + 1) * 16);
#pragma unroll
        for (int kk = 0; kk < 16; ++kk) {
            float a[RPT];
            if constexpr (RPT == 4) {
                *(float4*)a = *(const float4*)&As[cur][kk * R + ty * 4];
            } else if constexpr (RPT == 1) {
                a[0] = As[cur][kk * R + ty];
            } else {
                *(float4*)&a[0] = *(const float4*)&As[cur][kk * R + ty * 8];
                *(float4*)&a[4] = *(const float4*)&As[cur][kk * R + ty * 8 + 4];
            }
#pragma unroll
            for (int g = 0; g < NG; ++g) {
                float4 bb = *(const float4*)&Bs[cur][(kk * NG + g) * 64 + tx * 4];
                float bv[4] = {bb.x, bb.y, bb.z, bb.w};
#pragma unroll
                for (int ii = 0; ii < RPT; ++ii)
#pragma unroll
                    for (int jj = 0; jj < 4; ++jj)
                        acc[g][ii][jj] += a[ii] * bv[jj];
            }
        }
        if (more) {
            store(cur ^ 1);
            __syncthreads();
        }
    }

    // ----- epilogue -----
    if constexpr (NSEG == 3) {
        const size_t cLb = ((size_t)(2 * w) * BATCH) * LDIM;
        const size_t cRb = ((size_t)(2 * w + 1) * BATCH) * LDIM;
#pragma unroll
        for (int ii = 0; ii < RPT; ++ii) {
            int r  = row0 + ty * RPT + ii;
            int bb = r & 127;
            int nc = n0 + tx * 4;
            float4 cL = *(const float4*)&cChild[cLb + (size_t)bb * LDIM + nc];
            float4 cR = *(const float4*)&cChild[cRb + (size_t)bb * LDIM + nc];
            float cl4[4] = {cL.x, cL.y, cL.z, cL.w};
            float cr4[4] = {cR.x, cR.y, cR.z, cR.w};
            float4 c4, h4;
            float* cp = (float*)&c4; float* hp = (float*)&h4;
#pragma unroll
            for (int jj = 0; jj < 4; ++jj) {
                int n = nc + jj;
                float gi = sigmoidf_(acc[0][ii][jj] + bias[n]);
                float gu = tanhf(acc[1][ii][jj] + bias[256 + n]);
                float f0 = acc[2][ii][jj] + bias[512 + n];
                float f1 = acc[3][ii][jj] + bias[768 + n];
                float c  = gi * gu + f0 * cl4[jj] + f1 * cr4[jj];
                cp[jj] = c;
                hp[jj] = tanhf(c);
            }
            *(float4*)&cOut[(size_t)r * LDIM + nc] = c4;
            *(float4*)&hOut[(size_t)r * LDIM + nc] = h4;
        }
    } else {
#pragma unroll
        for (int ii = 0; ii < RPT; ++ii) {
            int r  = row0 + ty * RPT + ii;
            int nc = n0 + tx * 4;
            float4 c4, h4;
            float* cp = (float*)&c4; float* hp = (float*)&h4;
#pragma unroll
            for (int jj = 0; jj < 4; ++jj) {
                int n = nc + jj;
                float c = acc[0][ii][jj] + bias[n];
                float o = acc[1][ii][jj] + bias[256 + n];
                cp[jj] = c;
                hp[jj] = sigmoidf_(o) * tanhf(c);
            }
            *(float4*)&cOut[(size_t)r * LDIM + nc] = c4;
            *(float4*)&hOut[(size_t)r * LDIM + nc] = h4;
        }
    }
}

// ---------------------------------------------------------------------------
// Final: out[b][n] = tanh([init | c_root | h_root] @ Woend + boend). grid 128.
__global__ __launch_bounds__(256) void final_kernel(
    const float* __restrict__ init_emb,
    const float* __restrict__ cRoot, const float* __restrict__ hRoot,
    const float* __restrict__ Woend, const float* __restrict__ boend,
    float* __restrict__ out)
{
    __shared__ float sv[768];
    int b = blockIdx.x, t = threadIdx.x;
    sv[t]       = init_emb[(size_t)b * 256 + t];
    sv[256 + t] = cRoot[(size_t)b * 256 + t];
    sv[512 + t] = hRoot[(size_t)b * 256 + t];
    __syncthreads();
    float acc = boend[t];
#pragma unroll 4
    for (int d = 0; d < 768; ++d)
        acc += sv[d] * Woend[(size_t)d * 256 + t];
    out[(size_t)b * 256 + t] = tanhf(acc);
}

// ---------------------------------------------------------------------------
extern "C" void kernel_launch(void* const* d_in, const int* in_sizes, int n_in,
                              void* d_out, int out_size, void* d_ws, size_t ws_size,
                              hipStream_t stream)
{
    const float* x_embed  = (const float*)d_in[0];
    const float* init_emb = (const float*)d_in[1];
    const float* Wcx = (const float*)d_in[2];  const float* bcx = (const float*)d_in[3];
    const float* Wox = (const float*)d_in[4];  const float* box = (const float*)d_in[5];
    const float* Wix = (const float*)d_in[6];  const float* bix = (const float*)d_in[7];
    const float* Wfx = (const float*)d_in[8];  const float* bfx = (const float*)d_in[9];
    const float* Wux = (const float*)d_in[10]; const float* bux = (const float*)d_in[11];
    const float* Wi  = (const float*)d_in[12]; const float* bi  = (const float*)d_in[13];
    const float* Wf  = (const float*)d_in[14]; const float* bf  = (const float*)d_in[15];
    const float* Wu  = (const float*)d_in[16]; const float* bu  = (const float*)d_in[17];
    const float* Woend = (const float*)d_in[18]; const float* boend = (const float*)d_in[19];
    float* out = (float*)d_out;
    float* ws  = (float*)d_ws;

    size_t off = 0;
    float* hA = ws + off; off += (size_t)512 * 128 * 256;   // 64 MB: leaf/even-level h
    float* cA = ws + off; off += (size_t)512 * 128 * 256;
    float* hB = ws + off; off += (size_t)256 * 128 * 256;   // 32 MB
    float* cB = ws + off; off += (size_t)256 * 128 * 256;
    float* Wbig      = ws + off; off += (size_t)768 * 1024;
    float* bias_big  = ws + off; off += 1024;
    float* Wleaf     = ws + off; off += (size_t)256 * 512;
    float* bias_leaf = ws + off; off += 512;

    {
        int total = 768 * 1024 + 1024 + 256 * 512 + 512;
        int blocks = (total + 255) / 256;
        build_weights<<<blocks, 256, 0, stream>>>(
            Wix, bix, Wfx, bfx, Wux, bux, Wi, bi, Wf, bf, Wu, bu,
            Wcx, bcx, Wox, box, Wbig, bias_big, Wleaf, bias_leaf);
    }

    // Leaves: 65536 rows, K=256, 2 col groups. grid (1024, 4).
    gemm_fused<4, 2, 1><<<dim3(1024, 4), 256, 0, stream>>>(
        x_embed, nullptr, nullptr, Wleaf, bias_leaf, hA, cA, 511);

    float* hbufs[2] = {hA, hB};
    float* cbufs[2] = {cA, cB};
    int child = 0;  // leaves in A
    for (int lvl = 8; lvl >= 0; --lvl) {
        int W = 1 << lvl, s = W - 1;
        int outb = child ^ 1;
        if (W >= 128) {
            gemm_fused<4, 4, 3><<<dim3(W * 2, 4), 256, 0, stream>>>(
                x_embed, hbufs[child], cbufs[child], Wbig, bias_big,
                hbufs[outb], cbufs[outb], s);
        } else {
            gemm_fused<1, 4, 3><<<dim3(W * 8, 4), 256, 0, stream>>>(
                x_embed, hbufs[child], cbufs[child], Wbig, bias_big,
                hbufs[outb], cbufs[outb], s);
        }
        child = outb;
    }

    final_kernel<<<128, 256, 0, stream>>>(init_emb, cbufs[child], hbufs[child],
                                          Woend, boend, out);
}

// Round 3
// 3184.718 us; speedup vs baseline: 9.6862x; 9.6862x over previous
//
#include <hip/hip_runtime.h>
#include <hip/hip_bf16.h>
#include <math.h>

// Tree-LSTM "LogicEncoder": D=10, N=1023 nodes, B=128, LD=256, K=2.
// Round 3:
//  - Microtile 8x(4x4groups) / 16x(4x2groups): 6 ds_read_b128 per 128 FMA
//    (round-1 was 5 per 64 -> LDS-throughput-bound at 53%).
//  - Early-issued global loads (register staging), single LDS buffer,
//    2 barriers/K-step. NO __launch_bounds__ min-occupancy arg (round-2's
//    (256,4) forced VGPR=64 -> scratch spill -> 40GB writes/dispatch).
//  - Split-K (3 segments: x|hL|hR) + combine kernel for W<=64 levels,
//    gated on ws_size.
//  - fp32 throughout (absmax 0.0117 vs 0.02 threshold; bf16 noise would be
//    amplified ~1e5x through the un-squashed f*c recursion).

#define NNODES 1023
#define BATCH  128
#define LDIM   256

__device__ __forceinline__ float sigmoidf_(float x) {
    return 1.f / (1.f + expf(-x));
}

// ---------------------------------------------------------------------------
// Pack Wbig (768x1024) + bias_big(1024) + Wleaf(256x512) + bias_leaf(512).
__global__ __launch_bounds__(256) void build_weights(
    const float* __restrict__ Wix, const float* __restrict__ bix,
    const float* __restrict__ Wfx, const float* __restrict__ bfx,
    const float* __restrict__ Wux, const float* __restrict__ bux,
    const float* __restrict__ Wi,  const float* __restrict__ bi,
    const float* __restrict__ Wf,  const float* __restrict__ bf,
    const float* __restrict__ Wu,  const float* __restrict__ bu,
    const float* __restrict__ Wcx, const float* __restrict__ bcx,
    const float* __restrict__ Wox, const float* __restrict__ box,
    float* __restrict__ Wbig, float* __restrict__ bias_big,
    float* __restrict__ Wleaf, float* __restrict__ bias_leaf)
{
    int i = blockIdx.x * blockDim.x + threadIdx.x;
    if (i < 768 * 1024) {
        int k = i >> 10, n = i & 1023;
        int g = n >> 8, nn = n & 255;
        float v;
        if (g == 0) {
            v = (k < 256) ? Wix[k * 256 + nn]
              : (k < 512) ? Wi[(k - 256) * 256 + nn]
                          : Wi[65536 + (k - 512) * 256 + nn];
        } else if (g == 1) {
            v = (k < 256) ? Wux[k * 256 + nn]
              : (k < 512) ? Wu[(k - 256) * 256 + nn]
                          : Wu[65536 + (k - 512) * 256 + nn];
        } else {
            int kf = g - 2;  // f0 / f1
            v = (k < 256) ? Wfx[k * 256 + nn]
              : (k < 512) ? Wf[((kf * 2 + 0) * 256 + (k - 256)) * 256 + nn]
                          : Wf[((kf * 2 + 1) * 256 + (k - 512)) * 256 + nn];
        }
        Wbig[i] = v;
        return;
    }
    i -= 768 * 1024;
    if (i < 1024) {
        int g = i >> 8, nn = i & 255;
        float v;
        if (g == 0)      v = bix[nn] + bi[nn] + bi[256 + nn];
        else if (g == 1) v = bux[nn] + bu[nn] + bu[256 + nn];
        else if (g == 2) v = bfx[nn] + bf[nn] + bf[256 + nn];
        else             v = bfx[nn] + bf[512 + nn] + bf[768 + nn];
        bias_big[i] = v;
        return;
    }
    i -= 1024;
    if (i < 256 * 512) {
        int k = i >> 9, n = i & 511;
        Wleaf[i] = (n < 256) ? Wcx[k * 256 + n] : Wox[k * 256 + (n - 256)];
        return;
    }
    i -= 256 * 512;
    if (i < 512) {
        bias_leaf[i] = (i < 256) ? bcx[i] : box[i - 256];
    }
}

// ---------------------------------------------------------------------------
// Fused GEMM + LSTM epilogue.
//   TM:   rows per thread; block tile ROWS = 16*TM rows.
//   NG:   output col groups (4 = [i|u|f0|f1], 2 = [c|o] leaf); 4 cols/group/thread.
//   NSEG: K segments of 256 (3 = [x|hL|hR], 1 = x only).
// Block 256 threads (ty 0..15 rows, tx 0..15 cols). grid (rowBlocks, 4).
template<int TM, int NG, int NSEG>
__global__ __launch_bounds__(256) void gemm_fused(
    const float* __restrict__ x_embed,
    const float* __restrict__ hChild, const float* __restrict__ cChild,
    const float* __restrict__ Wmat, const float* __restrict__ bias,
    float* __restrict__ hOut, float* __restrict__ cOut, int nstart)
{
    constexpr int ROWS = 16 * TM;
    constexpr int NLV  = ROWS / 64;     // float4 A-loads per thread per K-step
    constexpr int AST  = ROWS + 4;      // padded A stride (breaks bank collisions)
    constexpr int BST  = NG * 64;
    constexpr int WLD  = NG * 256;
    constexpr int NIT  = NSEG * 16;
    __shared__ float As[16 * AST];
    __shared__ float Bs[16 * BST];

    const int tid = threadIdx.x;
    const int ty = tid >> 4, tx = tid & 15;
    const int bx = blockIdx.x;
    const int n0 = blockIdx.y * 64;
    const int lr = tid >> 2;            // A-load row (0..63)
    const int kq = (tid & 3) * 4;       // A-load k offset

    const float* pX[NLV];
    const float* pL[NLV];
    const float* pR[NLV];
#pragma unroll
    for (int i = 0; i < NLV; ++i) {
        int grl  = bx * ROWS + lr + 64 * i;
        int node = grl >> 7, b = grl & 127;
        pX[i] = x_embed + ((size_t)b * NNODES + (size_t)(nstart + node)) * LDIM + kq;
        if constexpr (NSEG == 3) {
            pL[i] = hChild + ((size_t)(2 * node) * BATCH + b) * LDIM + kq;
            pR[i] = pL[i] + (size_t)BATCH * LDIM;
        }
    }

    float acc[NG][TM][4];
#pragma unroll
    for (int g = 0; g < NG; ++g)
#pragma unroll
        for (int ii = 0; ii < TM; ++ii)
#pragma unroll
            for (int jj = 0; jj < 4; ++jj) acc[g][ii][jj] = 0.f;

    float4 av[NLV];
    float4 bv[NG];

    auto do_loads = [&](int it) {
        const int koff = (it * 16) & 255;
        if constexpr (NSEG == 3) {
            const int seg = it >> 4;
#pragma unroll
            for (int i = 0; i < NLV; ++i) {
                const float* p = (seg == 0) ? pX[i] : (seg == 1) ? pL[i] : pR[i];
                av[i] = *(const float4*)(p + koff);
            }
        } else {
#pragma unroll
            for (int i = 0; i < NLV; ++i) av[i] = *(const float4*)(pX[i] + koff);
        }
#pragma unroll
        for (int q = 0; q < NG; ++q) {
            int F  = q * 256 + tid;
            int kk = F / (NG * 16);
            int rem = F % (NG * 16);
            bv[q] = *(const float4*)(Wmat + (size_t)(it * 16 + kk) * WLD
                                     + (rem >> 4) * 256 + n0 + (rem & 15) * 4);
        }
    };

    do_loads(0);
    for (int it = 0; it < NIT; ++it) {
        if (it) __syncthreads();         // previous compute done before overwrite
#pragma unroll
        for (int i = 0; i < NLV; ++i) {
            int r = lr + 64 * i;
            As[(kq + 0) * AST + r] = av[i].x;
            As[(kq + 1) * AST + r] = av[i].y;
            As[(kq + 2) * AST + r] = av[i].z;
            As[(kq + 3) * AST + r] = av[i].w;
        }
#pragma unroll
        for (int q = 0; q < NG; ++q) {
            int F  = q * 256 + tid;
            int kk = F / (NG * 16);
            int rem = F % (NG * 16);
            *(float4*)&Bs[kk * BST + (rem >> 4) * 64 + (rem & 15) * 4] = bv[q];
        }
        __syncthreads();
        if (it + 1 < NIT) do_loads(it + 1);   // hide global latency under FMAs
#pragma unroll
        for (int kk = 0; kk < 16; ++kk) {
            float a[TM];
#pragma unroll
            for (int u = 0; u < TM / 4; ++u)
                *(float4*)&a[u * 4] = *(const float4*)&As[kk * AST + ty * TM + u * 4];
#pragma unroll
            for (int g = 0; g < NG; ++g) {
                float4 bb = *(const float4*)&Bs[kk * BST + g * 64 + tx * 4];
                float bj[4] = {bb.x, bb.y, bb.z, bb.w};
#pragma unroll
                for (int ii = 0; ii < TM; ++ii)
#pragma unroll
                    for (int jj = 0; jj < 4; ++jj)
                        acc[g][ii][jj] += a[ii] * bj[jj];
            }
        }
    }

    // ----- epilogue -----
#pragma unroll
    for (int ii = 0; ii < TM; ++ii) {
        int rl = ty * TM + ii;
        int gr = bx * ROWS + rl;
        int nc = n0 + tx * 4;
        float4 c4, h4;
        float* cp = (float*)&c4; float* hp = (float*)&h4;
        if constexpr (NSEG == 3) {
            int node = gr >> 7, b = gr & 127;
            float4 cL = *(const float4*)&cChild[((size_t)(2 * node) * BATCH + b) * LDIM + nc];
            float4 cR = *(const float4*)&cChild[((size_t)(2 * node + 1) * BATCH + b) * LDIM + nc];
            float cl4[4] = {cL.x, cL.y, cL.z, cL.w};
            float cr4[4] = {cR.x, cR.y, cR.z, cR.w};
#pragma unroll
            for (int jj = 0; jj < 4; ++jj) {
                int n = nc + jj;
                float gi = sigmoidf_(acc[0][ii][jj] + bias[n]);
                float gu = tanhf(acc[1][ii][jj] + bias[256 + n]);
                float f0 = acc[2][ii][jj] + bias[512 + n];
                float f1 = acc[3][ii][jj] + bias[768 + n];
                float c  = gi * gu + f0 * cl4[jj] + f1 * cr4[jj];
                cp[jj] = c;
                hp[jj] = tanhf(c);
            }
        } else {
#pragma unroll
            for (int jj = 0; jj < 4; ++jj) {
                int n = nc + jj;
                float c = acc[0][ii][jj] + bias[n];
                float o = acc[1][ii][jj] + bias[256 + n];
                cp[jj] = c;
                hp[jj] = sigmoidf_(o) * tanhf(c);
            }
        }
        *(float4*)&cOut[(size_t)gr * LDIM + nc] = c4;
        *(float4*)&hOut[(size_t)gr * LDIM + nc] = h4;
    }
}

// ---------------------------------------------------------------------------
// Split-K partial GEMM: one 256-wide K segment (blockIdx.z: 0=x, 1=hL, 2=hR).
// TM=8, NG=4. Raw partial sums -> part[seg][row][1024]. grid (W, 4, 3).
__global__ __launch_bounds__(256) void gemm_part(
    const float* __restrict__ x_embed, const float* __restrict__ hChild,
    const float* __restrict__ Wbig,
    float* __restrict__ part, int nstart, int rowsTotal)
{
    constexpr int TM = 8, NG = 4, ROWS = 128, NLV = 2, AST = 132, BST = 256;
    __shared__ float As[16 * AST];
    __shared__ float Bs[16 * BST];

    const int tid = threadIdx.x;
    const int ty = tid >> 4, tx = tid & 15;
    const int bx = blockIdx.x;
    const int n0 = blockIdx.y * 64;
    const int seg = blockIdx.z;
    const int lr = tid >> 2;
    const int kq = (tid & 3) * 4;

    const float* pA[NLV];
#pragma unroll
    for (int i = 0; i < NLV; ++i) {
        int grl  = bx * ROWS + lr + 64 * i;
        int node = grl >> 7, b = grl & 127;
        if (seg == 0)
            pA[i] = x_embed + ((size_t)b * NNODES + (size_t)(nstart + node)) * LDIM + kq;
        else
            pA[i] = hChild + ((size_t)(2 * node + (seg - 1)) * BATCH + b) * LDIM + kq;
    }

    float acc[NG][TM][4];
#pragma unroll
    for (int g = 0; g < NG; ++g)
#pragma unroll
        for (int ii = 0; ii < TM; ++ii)
#pragma unroll
            for (int jj = 0; jj < 4; ++jj) acc[g][ii][jj] = 0.f;

    float4 av[NLV];
    float4 bv[NG];
    auto do_loads = [&](int it) {
        const int koff = it * 16;
#pragma unroll
        for (int i = 0; i < NLV; ++i) av[i] = *(const float4*)(pA[i] + koff);
#pragma unroll
        for (int q = 0; q < NG; ++q) {
            int F  = q * 256 + tid;
            int kk = F >> 6;
            int rem = F & 63;
            bv[q] = *(const float4*)(Wbig + (size_t)(seg * 256 + it * 16 + kk) * 1024
                                     + (rem >> 4) * 256 + n0 + (rem & 15) * 4);
        }
    };

    do_loads(0);
    for (int it = 0; it < 16; ++it) {
        if (it) __syncthreads();
#pragma unroll
        for (int i = 0; i < NLV; ++i) {
            int r = lr + 64 * i;
            As[(kq + 0) * AST + r] = av[i].x;
            As[(kq + 1) * AST + r] = av[i].y;
            As[(kq + 2) * AST + r] = av[i].z;
            As[(kq + 3) * AST + r] = av[i].w;
        }
#pragma unroll
        for (int q = 0; q < NG; ++q) {
            int F  = q * 256 + tid;
            int kk = F >> 6;
            int rem = F & 63;
            *(float4*)&Bs[kk * BST + (rem >> 4) * 64 + (rem & 15) * 4] = bv[q];
        }
        __syncthreads();
        if (it + 1 < 16) do_loads(it + 1);
#pragma unroll
        for (int kk = 0; kk < 16; ++kk) {
            float a[TM];
#pragma unroll
            for (int u = 0; u < 2; ++u)
                *(float4*)&a[u * 4] = *(const float4*)&As[kk * AST + ty * TM + u * 4];
#pragma unroll
            for (int g = 0; g < NG; ++g) {
                float4 bb = *(const float4*)&Bs[kk * BST + g * 64 + tx * 4];
                float bj[4] = {bb.x, bb.y, bb.z, bb.w};
#pragma unroll
                for (int ii = 0; ii < TM; ++ii)
#pragma unroll
                    for (int jj = 0; jj < 4; ++jj)
                        acc[g][ii][jj] += a[ii] * bj[jj];
            }
        }
    }
#pragma unroll
    for (int ii = 0; ii < TM; ++ii) {
        int gr = bx * ROWS + ty * TM + ii;
        size_t base = ((size_t)seg * rowsTotal + gr) * 1024 + n0 + tx * 4;
#pragma unroll
        for (int g = 0; g < NG; ++g)
            *(float4*)&part[base + g * 256] = *(float4*)acc[g][ii];
    }
}

// ---------------------------------------------------------------------------
// Combine 3 split-K partials + LSTM epilogue. grid (rows/4), block 256.
__global__ __launch_bounds__(256) void combine_eps(
    const float* __restrict__ part, const float* __restrict__ cChild,
    const float* __restrict__ bias,
    float* __restrict__ hOut, float* __restrict__ cOut, int rowsTotal)
{
    int idx = blockIdx.x * 256 + threadIdx.x;     // over rowsTotal*64
    int row = idx >> 6, n = (idx & 63) * 4;
    size_t sseg = (size_t)rowsTotal * 1024;
    const float* p0 = part + (size_t)row * 1024 + n;
    float s[4][4];
#pragma unroll
    for (int g = 0; g < 4; ++g) {
        float4 a = *(const float4*)(p0 + g * 256);
        float4 b = *(const float4*)(p0 + sseg + g * 256);
        float4 c = *(const float4*)(p0 + 2 * sseg + g * 256);
        s[g][0] = a.x + b.x + c.x; s[g][1] = a.y + b.y + c.y;
        s[g][2] = a.z + b.z + c.z; s[g][3] = a.w + b.w + c.w;
    }
    int node = row >> 7, b = row & 127;
    float4 cL = *(const float4*)&cChild[((size_t)(2 * node) * BATCH + b) * LDIM + n];
    float4 cR = *(const float4*)&cChild[((size_t)(2 * node + 1) * BATCH + b) * LDIM + n];
    float cl4[4] = {cL.x, cL.y, cL.z, cL.w};
    float cr4[4] = {cR.x, cR.y, cR.z, cR.w};
    float4 c4, h4;
    float* cp = (float*)&c4; float* hp = (float*)&h4;
#pragma unroll
    for (int jj = 0; jj < 4; ++jj) {
        int nn = n + jj;
        float gi = sigmoidf_(s[0][jj] + bias[nn]);
        float gu = tanhf(s[1][jj] + bias[256 + nn]);
        float f0 = s[2][jj] + bias[512 + nn];
        float f1 = s[3][jj] + bias[768 + nn];
        float c  = gi * gu + f0 * cl4[jj] + f1 * cr4[jj];
        cp[jj] = c;
        hp[jj] = tanhf(c);
    }
    *(float4*)&cOut[(size_t)row * LDIM + n] = c4;
    *(float4*)&hOut[(size_t)row * LDIM + n] = h4;
}

// ---------------------------------------------------------------------------
// Final: out[b][n] = tanh([init | c_root | h_root] @ Woend + boend). grid 128.
__global__ __launch_bounds__(256) void final_kernel(
    const float* __restrict__ init_emb,
    const float* __restrict__ cRoot, const float* __restrict__ hRoot,
    const float* __restrict__ Woend, const float* __restrict__ boend,
    float* __restrict__ out)
{
    __shared__ float sv[768];
    int b = blockIdx.x, t = threadIdx.x;
    sv[t]       = init_emb[(size_t)b * 256 + t];
    sv[256 + t] = cRoot[(size_t)b * 256 + t];
    sv[512 + t] = hRoot[(size_t)b * 256 + t];
    __syncthreads();
    float acc = boend[t];
#pragma unroll 4
    for (int d = 0; d < 768; ++d)
        acc += sv[d] * Woend[(size_t)d * 256 + t];
    out[(size_t)b * 256 + t] = tanhf(acc);
}

// ---------------------------------------------------------------------------
extern "C" void kernel_launch(void* const* d_in, const int* in_sizes, int n_in,
                              void* d_out, int out_size, void* d_ws, size_t ws_size,
                              hipStream_t stream)
{
    const float* x_embed  = (const float*)d_in[0];
    const float* init_emb = (const float*)d_in[1];
    const float* Wcx = (const float*)d_in[2];  const float* bcx = (const float*)d_in[3];
    const float* Wox = (const float*)d_in[4];  const float* box = (const float*)d_in[5];
    const float* Wix = (const float*)d_in[6];  const float* bix = (const float*)d_in[7];
    const float* Wfx = (const float*)d_in[8];  const float* bfx = (const float*)d_in[9];
    const float* Wux = (const float*)d_in[10]; const float* bux = (const float*)d_in[11];
    const float* Wi  = (const float*)d_in[12]; const float* bi  = (const float*)d_in[13];
    const float* Wf  = (const float*)d_in[14]; const float* bf  = (const float*)d_in[15];
    const float* Wu  = (const float*)d_in[16]; const float* bu  = (const float*)d_in[17];
    const float* Woend = (const float*)d_in[18]; const float* boend = (const float*)d_in[19];
    float* out = (float*)d_out;
    float* ws  = (float*)d_ws;

    size_t off = 0;
    float* hA = ws + off; off += (size_t)512 * 128 * 256;
    float* cA = ws + off; off += (size_t)512 * 128 * 256;
    float* hB = ws + off; off += (size_t)256 * 128 * 256;
    float* cB = ws + off; off += (size_t)256 * 128 * 256;
    float* Wbig      = ws + off; off += (size_t)768 * 1024;
    float* bias_big  = ws + off; off += 1024;
    float* Wleaf     = ws + off; off += (size_t)256 * 512;
    float* bias_leaf = ws + off; off += 512;
    size_t part_off = off;
    float* part = ws + part_off;

    {
        int total = 768 * 1024 + 1024 + 256 * 512 + 512;
        int blocks = (total + 255) / 256;
        build_weights<<<blocks, 256, 0, stream>>>(
            Wix, bix, Wfx, bfx, Wux, bux, Wi, bi, Wf, bf, Wu, bu,
            Wcx, bcx, Wox, box, Wbig, bias_big, Wleaf, bias_leaf);
    }

    // Leaves: 65536 rows, K=256, NG=2 (c|o), TM=16 -> 256-row tiles. grid (256,4).
    gemm_fused<16, 2, 1><<<dim3(256, 4), 256, 0, stream>>>(
        x_embed, nullptr, nullptr, Wleaf, bias_leaf, hA, cA, 511);

    float* hbufs[2] = {hA, hB};
    float* cbufs[2] = {cA, cB};
    int child = 0;  // leaves in A
    for (int lvl = 8; lvl >= 0; --lvl) {
        int W = 1 << lvl, s = W - 1;
        int outb = child ^ 1;
        size_t rows = (size_t)W * 128;
        bool split = (W <= 64) &&
                     ((part_off + 3 * rows * 1024) * sizeof(float) <= ws_size);
        if (split) {
            gemm_part<<<dim3(W, 4, 3), 256, 0, stream>>>(
                x_embed, hbufs[child], Wbig, part, s, (int)rows);
            combine_eps<<<(int)(rows / 4), 256, 0, stream>>>(
                part, cbufs[child], bias_big, hbufs[outb], cbufs[outb], (int)rows);
        } else if (W >= 8) {
            gemm_fused<8, 4, 3><<<dim3(W, 4), 256, 0, stream>>>(
                x_embed, hbufs[child], cbufs[child], Wbig, bias_big,
                hbufs[outb], cbufs[outb], s);
        } else {
            gemm_fused<4, 4, 3><<<dim3(W * 2, 4), 256, 0, stream>>>(
                x_embed, hbufs[child], cbufs[child], Wbig, bias_big,
                hbufs[outb], cbufs[outb], s);
        }
        child = outb;
    }

    final_kernel<<<128, 256, 0, stream>>>(init_emb, cbufs[child], hbufs[child],
                                          Woend, boend, out);
}

// Round 4
// 1810.862 us; speedup vs baseline: 17.0348x; 1.7587x over previous
//
#include <hip/hip_runtime.h>
#include <hip/hip_bf16.h>
#include <math.h>

// Tree-LSTM "LogicEncoder": D=10, N=1023 nodes, B=128, LD=256, K=2.
// Round 4: recovery round.
//  - Leaf/level GEMMs = round-1 proven bodies (TM=4 microtile, VGPR~72,
//    occ ~30%, 82-85 TF). Round-3's TM=8/16 pushed VGPR to 184 -> 8 waves/CU
//    -> latency-bound collapse (occupancy 6-12%, 2-6x slower).
//  - Split-K over the 3 natural 256-wide K segments for W<=32 tail levels,
//    with the SAME TM=4 microtile + elementwise combine.
//  - fp32 throughout (absmax 0.0117 vs 0.02; rounding noise is amplified
//    ~linearly through the un-squashed f*c recursion, so bf16-family MFMA
//    paths would overshoot the threshold).
//  - Precise tanhf/expf in epilogues only.

#define NNODES 1023
#define BATCH  128
#define LDIM   256

__device__ __forceinline__ float sigmoidf_(float x) {
    return 1.f / (1.f + expf(-x));
}

// ---------------------------------------------------------------------------
// Pack Wbig (768x1024) + bias_big(1024) + Wleaf(256x512) + bias_leaf(512).
__global__ __launch_bounds__(256) void build_weights(
    const float* __restrict__ Wix, const float* __restrict__ bix,
    const float* __restrict__ Wfx, const float* __restrict__ bfx,
    const float* __restrict__ Wux, const float* __restrict__ bux,
    const float* __restrict__ Wi,  const float* __restrict__ bi,
    const float* __restrict__ Wf,  const float* __restrict__ bf,
    const float* __restrict__ Wu,  const float* __restrict__ bu,
    const float* __restrict__ Wcx, const float* __restrict__ bcx,
    const float* __restrict__ Wox, const float* __restrict__ box,
    float* __restrict__ Wbig, float* __restrict__ bias_big,
    float* __restrict__ Wleaf, float* __restrict__ bias_leaf)
{
    int i = blockIdx.x * blockDim.x + threadIdx.x;
    if (i < 768 * 1024) {
        int k = i >> 10, n = i & 1023;
        int g = n >> 8, nn = n & 255;
        float v;
        if (g == 0) {
            v = (k < 256) ? Wix[k * 256 + nn]
              : (k < 512) ? Wi[(k - 256) * 256 + nn]
                          : Wi[65536 + (k - 512) * 256 + nn];
        } else if (g == 1) {
            v = (k < 256) ? Wux[k * 256 + nn]
              : (k < 512) ? Wu[(k - 256) * 256 + nn]
                          : Wu[65536 + (k - 512) * 256 + nn];
        } else {
            int kf = g - 2;  // f0 / f1
            v = (k < 256) ? Wfx[k * 256 + nn]
              : (k < 512) ? Wf[((kf * 2 + 0) * 256 + (k - 256)) * 256 + nn]
                          : Wf[((kf * 2 + 1) * 256 + (k - 512)) * 256 + nn];
        }
        Wbig[i] = v;
        return;
    }
    i -= 768 * 1024;
    if (i < 1024) {
        int g = i >> 8, nn = i & 255;
        float v;
        if (g == 0)      v = bix[nn] + bi[nn] + bi[256 + nn];
        else if (g == 1) v = bux[nn] + bu[nn] + bu[256 + nn];
        else if (g == 2) v = bfx[nn] + bf[nn] + bf[256 + nn];
        else             v = bfx[nn] + bf[512 + nn] + bf[768 + nn];
        bias_big[i] = v;
        return;
    }
    i -= 1024;
    if (i < 256 * 512) {
        int k = i >> 9, n = i & 511;
        Wleaf[i] = (n < 256) ? Wcx[k * 256 + n] : Wox[k * 256 + (n - 256)];
        return;
    }
    i -= 256 * 512;
    if (i < 512) {
        bias_leaf[i] = (i < 256) ? bcx[i] : box[i - 256];
    }
}

// ---------------------------------------------------------------------------
// Leaf kernel (round-1 proven): rows r = w*128+b, A = x_embed row (K=256),
// 2 col groups (c|o), fused h/c epilogue. grid (1024, 4), block 256.
__global__ __launch_bounds__(256) void leaf_kernel(
    const float* __restrict__ x_embed,
    const float* __restrict__ Wleaf, const float* __restrict__ bias_leaf,
    float* __restrict__ hOut, float* __restrict__ cOut)
{
    __shared__ float As[16 * 68];
    __shared__ float Bs[2 * 16 * 64];
    float acc[2][4][4] = {};
    const int tid = threadIdx.x;
    const int ty = tid >> 4, tx = tid & 15;
    const int row0 = blockIdx.x * 64;
    const int n0 = blockIdx.y * 64;
    const int w = row0 >> 7;
    const int ar = tid >> 2;
    const int kq = (tid & 3) * 4;
    const int b = (row0 + ar) & 127;
    const float* xrow = x_embed + ((size_t)b * NNODES + 511 + w) * LDIM;

    for (int k0 = 0; k0 < 256; k0 += 16) {
        float4 av = *(const float4*)(xrow + k0 + kq);
        As[(kq + 0) * 68 + ar] = av.x;
        As[(kq + 1) * 68 + ar] = av.y;
        As[(kq + 2) * 68 + ar] = av.z;
        As[(kq + 3) * 68 + ar] = av.w;
#pragma unroll
        for (int q = 0; q < 2; ++q) {
            int L = q * 256 + tid;
            int g = L >> 8, kk = (L >> 4) & 15, n4 = (L & 15) * 4;
            float4 bv = *(const float4*)(Wleaf + (size_t)(k0 + kk) * 512 + g * 256 + n0 + n4);
            *(float4*)&Bs[(g * 16 + kk) * 64 + n4] = bv;
        }
        __syncthreads();
#pragma unroll
        for (int kk = 0; kk < 16; ++kk) {
            float4 a = *(const float4*)&As[kk * 68 + ty * 4];
            float av4[4] = {a.x, a.y, a.z, a.w};
#pragma unroll
            for (int g = 0; g < 2; ++g) {
                float4 bb = *(const float4*)&Bs[(g * 16 + kk) * 64 + tx * 4];
                float bv4[4] = {bb.x, bb.y, bb.z, bb.w};
#pragma unroll
                for (int ii = 0; ii < 4; ++ii)
#pragma unroll
                    for (int jj = 0; jj < 4; ++jj)
                        acc[g][ii][jj] += av4[ii] * bv4[jj];
            }
        }
        __syncthreads();
    }
#pragma unroll
    for (int ii = 0; ii < 4; ++ii) {
        int r = row0 + ty * 4 + ii;
        int nc = n0 + tx * 4;
        float4 c4, h4;
        float* cp = (float*)&c4; float* hp = (float*)&h4;
#pragma unroll
        for (int jj = 0; jj < 4; ++jj) {
            int n = nc + jj;
            float ac = acc[0][ii][jj] + bias_leaf[n];
            float ao = acc[1][ii][jj] + bias_leaf[256 + n];
            cp[jj] = ac;
            hp[jj] = sigmoidf_(ao) * tanhf(ac);
        }
        *(float4*)&cOut[(size_t)r * LDIM + nc] = c4;
        *(float4*)&hOut[(size_t)r * LDIM + nc] = h4;
    }
}

// ---------------------------------------------------------------------------
// Level kernel (round-1 proven): A row = [x | hL | hR] (K=768), 4 col groups
// [i|u|f0|f1], fused LSTM epilogue. grid (W*2, 4), block 256.
__global__ __launch_bounds__(256) void level_kernel(
    const float* __restrict__ x_embed,
    const float* __restrict__ hChild, const float* __restrict__ cChild,
    const float* __restrict__ Wbig, const float* __restrict__ bias_big,
    float* __restrict__ hOut, float* __restrict__ cOut,
    int nstart)
{
    __shared__ float As[16 * 68];
    __shared__ float Bs[4 * 16 * 64];
    float acc[4][4][4] = {};
    const int tid = threadIdx.x;
    const int ty = tid >> 4, tx = tid & 15;
    const int row0 = blockIdx.x * 64;
    const int n0 = blockIdx.y * 64;
    const int w = row0 >> 7;
    const int ar = tid >> 2;
    const int kq = (tid & 3) * 4;
    const int b = (row0 + ar) & 127;
    const float* srcX = x_embed + ((size_t)b * NNODES + nstart + w) * LDIM;
    const float* srcL = hChild + ((size_t)(2 * w) * BATCH + b) * LDIM;
    const float* srcR = hChild + ((size_t)(2 * w + 1) * BATCH + b) * LDIM;

    for (int k0 = 0; k0 < 768; k0 += 16) {
        int seg = k0 >> 8, off = k0 & 255;
        const float* src = (seg == 0) ? srcX : (seg == 1) ? srcL : srcR;
        float4 av = *(const float4*)(src + off + kq);
        As[(kq + 0) * 68 + ar] = av.x;
        As[(kq + 1) * 68 + ar] = av.y;
        As[(kq + 2) * 68 + ar] = av.z;
        As[(kq + 3) * 68 + ar] = av.w;
#pragma unroll
        for (int q = 0; q < 4; ++q) {
            int L = q * 256 + tid;
            int g = L >> 8, kk = (L >> 4) & 15, n4 = (L & 15) * 4;
            float4 bv = *(const float4*)(Wbig + (size_t)(k0 + kk) * 1024 + g * 256 + n0 + n4);
            *(float4*)&Bs[(g * 16 + kk) * 64 + n4] = bv;
        }
        __syncthreads();
#pragma unroll
        for (int kk = 0; kk < 16; ++kk) {
            float4 a = *(const float4*)&As[kk * 68 + ty * 4];
            float av4[4] = {a.x, a.y, a.z, a.w};
#pragma unroll
            for (int g = 0; g < 4; ++g) {
                float4 bb = *(const float4*)&Bs[(g * 16 + kk) * 64 + tx * 4];
                float bv4[4] = {bb.x, bb.y, bb.z, bb.w};
#pragma unroll
                for (int ii = 0; ii < 4; ++ii)
#pragma unroll
                    for (int jj = 0; jj < 4; ++jj)
                        acc[g][ii][jj] += av4[ii] * bv4[jj];
            }
        }
        __syncthreads();
    }
    const size_t cLbase = ((size_t)(2 * w) * BATCH) * LDIM;
    const size_t cRbase = ((size_t)(2 * w + 1) * BATCH) * LDIM;
#pragma unroll
    for (int ii = 0; ii < 4; ++ii) {
        int r = row0 + ty * 4 + ii;
        int bb2 = r & 127;
        int nc = n0 + tx * 4;
        float4 cL = *(const float4*)&cChild[cLbase + (size_t)bb2 * LDIM + nc];
        float4 cR = *(const float4*)&cChild[cRbase + (size_t)bb2 * LDIM + nc];
        float cl4[4] = {cL.x, cL.y, cL.z, cL.w};
        float cr4[4] = {cR.x, cR.y, cR.z, cR.w};
        float4 c4, h4;
        float* cp = (float*)&c4; float* hp = (float*)&h4;
#pragma unroll
        for (int jj = 0; jj < 4; ++jj) {
            int n = nc + jj;
            float gi = sigmoidf_(acc[0][ii][jj] + bias_big[n]);
            float gu = tanhf(acc[1][ii][jj] + bias_big[256 + n]);
            float f0 = acc[2][ii][jj] + bias_big[512 + n];
            float f1 = acc[3][ii][jj] + bias_big[768 + n];
            float c = gi * gu + f0 * cl4[jj] + f1 * cr4[jj];
            cp[jj] = c;
            hp[jj] = tanhf(c);
        }
        *(float4*)&cOut[(size_t)r * LDIM + nc] = c4;
        *(float4*)&hOut[(size_t)r * LDIM + nc] = h4;
    }
}

// ---------------------------------------------------------------------------
// Split-K partial (TM=4 microtile, one 256-wide K segment per blockIdx.z).
// Writes raw partials part[seg][row][1024]. grid (W*2, 4, 3), block 256.
__global__ __launch_bounds__(256) void gemm_part4(
    const float* __restrict__ x_embed, const float* __restrict__ hChild,
    const float* __restrict__ Wbig,
    float* __restrict__ part, int nstart, int rowsTotal)
{
    __shared__ float As[16 * 68];
    __shared__ float Bs[4 * 16 * 64];
    float acc[4][4][4] = {};
    const int tid = threadIdx.x;
    const int ty = tid >> 4, tx = tid & 15;
    const int row0 = blockIdx.x * 64;
    const int n0 = blockIdx.y * 64;
    const int seg = blockIdx.z;
    const int w = row0 >> 7;
    const int ar = tid >> 2;
    const int kq = (tid & 3) * 4;
    const int b = (row0 + ar) & 127;
    const float* src =
        (seg == 0) ? x_embed + ((size_t)b * NNODES + nstart + w) * LDIM
                   : hChild + ((size_t)(2 * w + (seg - 1)) * BATCH + b) * LDIM;

    for (int k0 = 0; k0 < 256; k0 += 16) {
        float4 av = *(const float4*)(src + k0 + kq);
        As[(kq + 0) * 68 + ar] = av.x;
        As[(kq + 1) * 68 + ar] = av.y;
        As[(kq + 2) * 68 + ar] = av.z;
        As[(kq + 3) * 68 + ar] = av.w;
#pragma unroll
        for (int q = 0; q < 4; ++q) {
            int L = q * 256 + tid;
            int g = L >> 8, kk = (L >> 4) & 15, n4 = (L & 15) * 4;
            float4 bv = *(const float4*)(Wbig + (size_t)(seg * 256 + k0 + kk) * 1024
                                         + g * 256 + n0 + n4);
            *(float4*)&Bs[(g * 16 + kk) * 64 + n4] = bv;
        }
        __syncthreads();
#pragma unroll
        for (int kk = 0; kk < 16; ++kk) {
            float4 a = *(const float4*)&As[kk * 68 + ty * 4];
            float av4[4] = {a.x, a.y, a.z, a.w};
#pragma unroll
            for (int g = 0; g < 4; ++g) {
                float4 bb = *(const float4*)&Bs[(g * 16 + kk) * 64 + tx * 4];
                float bv4[4] = {bb.x, bb.y, bb.z, bb.w};
#pragma unroll
                for (int ii = 0; ii < 4; ++ii)
#pragma unroll
                    for (int jj = 0; jj < 4; ++jj)
                        acc[g][ii][jj] += av4[ii] * bv4[jj];
            }
        }
        __syncthreads();
    }
#pragma unroll
    for (int ii = 0; ii < 4; ++ii) {
        int r = row0 + ty * 4 + ii;
        size_t base = ((size_t)seg * rowsTotal + r) * 1024 + n0 + tx * 4;
#pragma unroll
        for (int g = 0; g < 4; ++g)
            *(float4*)&part[base + g * 256] = *(float4*)acc[g][ii];
    }
}

// ---------------------------------------------------------------------------
// Combine 3 split-K partials + LSTM epilogue. grid (rows/4), block 256.
__global__ __launch_bounds__(256) void combine_eps(
    const float* __restrict__ part, const float* __restrict__ cChild,
    const float* __restrict__ bias,
    float* __restrict__ hOut, float* __restrict__ cOut, int rowsTotal)
{
    int idx = blockIdx.x * 256 + threadIdx.x;     // over rowsTotal*64
    int row = idx >> 6, n = (idx & 63) * 4;
    size_t sseg = (size_t)rowsTotal * 1024;
    const float* p0 = part + (size_t)row * 1024 + n;
    float s[4][4];
#pragma unroll
    for (int g = 0; g < 4; ++g) {
        float4 a = *(const float4*)(p0 + g * 256);
        float4 b = *(const float4*)(p0 + sseg + g * 256);
        float4 c = *(const float4*)(p0 + 2 * sseg + g * 256);
        s[g][0] = a.x + b.x + c.x; s[g][1] = a.y + b.y + c.y;
        s[g][2] = a.z + b.z + c.z; s[g][3] = a.w + b.w + c.w;
    }
    int node = row >> 7, b = row & 127;
    float4 cL = *(const float4*)&cChild[((size_t)(2 * node) * BATCH + b) * LDIM + n];
    float4 cR = *(const float4*)&cChild[((size_t)(2 * node + 1) * BATCH + b) * LDIM + n];
    float cl4[4] = {cL.x, cL.y, cL.z, cL.w};
    float cr4[4] = {cR.x, cR.y, cR.z, cR.w};
    float4 c4, h4;
    float* cp = (float*)&c4; float* hp = (float*)&h4;
#pragma unroll
    for (int jj = 0; jj < 4; ++jj) {
        int nn = n + jj;
        float gi = sigmoidf_(s[0][jj] + bias[nn]);
        float gu = tanhf(s[1][jj] + bias[256 + nn]);
        float f0 = s[2][jj] + bias[512 + nn];
        float f1 = s[3][jj] + bias[768 + nn];
        float c = gi * gu + f0 * cl4[jj] + f1 * cr4[jj];
        cp[jj] = c;
        hp[jj] = tanhf(c);
    }
    *(float4*)&cOut[(size_t)row * LDIM + n] = c4;
    *(float4*)&hOut[(size_t)row * LDIM + n] = h4;
}

// ---------------------------------------------------------------------------
// Final: out[b][n] = tanh([init | c_root | h_root] @ Woend + boend). grid 128.
__global__ __launch_bounds__(256) void final_kernel(
    const float* __restrict__ init_emb,
    const float* __restrict__ cRoot, const float* __restrict__ hRoot,
    const float* __restrict__ Woend, const float* __restrict__ boend,
    float* __restrict__ out)
{
    __shared__ float sv[768];
    int b = blockIdx.x, t = threadIdx.x;
    sv[t]       = init_emb[(size_t)b * 256 + t];
    sv[256 + t] = cRoot[(size_t)b * 256 + t];
    sv[512 + t] = hRoot[(size_t)b * 256 + t];
    __syncthreads();
    float acc = boend[t];
#pragma unroll 4
    for (int d = 0; d < 768; ++d)
        acc += sv[d] * Woend[(size_t)d * 256 + t];
    out[(size_t)b * 256 + t] = tanhf(acc);
}

// ---------------------------------------------------------------------------
extern "C" void kernel_launch(void* const* d_in, const int* in_sizes, int n_in,
                              void* d_out, int out_size, void* d_ws, size_t ws_size,
                              hipStream_t stream)
{
    const float* x_embed  = (const float*)d_in[0];
    const float* init_emb = (const float*)d_in[1];
    const float* Wcx = (const float*)d_in[2];  const float* bcx = (const float*)d_in[3];
    const float* Wox = (const float*)d_in[4];  const float* box = (const float*)d_in[5];
    const float* Wix = (const float*)d_in[6];  const float* bix = (const float*)d_in[7];
    const float* Wfx = (const float*)d_in[8];  const float* bfx = (const float*)d_in[9];
    const float* Wux = (const float*)d_in[10]; const float* bux = (const float*)d_in[11];
    const float* Wi  = (const float*)d_in[12]; const float* bi  = (const float*)d_in[13];
    const float* Wf  = (const float*)d_in[14]; const float* bf  = (const float*)d_in[15];
    const float* Wu  = (const float*)d_in[16]; const float* bu  = (const float*)d_in[17];
    const float* Woend = (const float*)d_in[18]; const float* boend = (const float*)d_in[19];
    float* out = (float*)d_out;
    float* ws  = (float*)d_ws;

    size_t off = 0;
    float* hA = ws + off; off += (size_t)512 * 128 * 256;
    float* cA = ws + off; off += (size_t)512 * 128 * 256;
    float* hB = ws + off; off += (size_t)256 * 128 * 256;
    float* cB = ws + off; off += (size_t)256 * 128 * 256;
    float* Wbig      = ws + off; off += (size_t)768 * 1024;
    float* bias_big  = ws + off; off += 1024;
    float* Wleaf     = ws + off; off += (size_t)256 * 512;
    float* bias_leaf = ws + off; off += 512;
    size_t part_off = off;
    float* part = ws + part_off;

    {
        int total = 768 * 1024 + 1024 + 256 * 512 + 512;
        int blocks = (total + 255) / 256;
        build_weights<<<blocks, 256, 0, stream>>>(
            Wix, bix, Wfx, bfx, Wux, bux, Wi, bi, Wf, bf, Wu, bu,
            Wcx, bcx, Wox, box, Wbig, bias_big, Wleaf, bias_leaf);
    }

    leaf_kernel<<<dim3(1024, 4), 256, 0, stream>>>(x_embed, Wleaf, bias_leaf, hA, cA);

    float* hbufs[2] = {hA, hB};
    float* cbufs[2] = {cA, cB};
    int child = 0;  // leaves in A
    for (int lvl = 8; lvl >= 0; --lvl) {
        int W = 1 << lvl, s = W - 1;
        int outb = child ^ 1;
        size_t rows = (size_t)W * 128;
        bool split = (W <= 32) &&
                     ((part_off + 3 * rows * 1024) * sizeof(float) <= ws_size);
        if (split) {
            gemm_part4<<<dim3(W * 2, 4, 3), 256, 0, stream>>>(
                x_embed, hbufs[child], Wbig, part, s, (int)rows);
            combine_eps<<<(int)(rows / 4), 256, 0, stream>>>(
                part, cbufs[child], bias_big, hbufs[outb], cbufs[outb], (int)rows);
        } else {
            level_kernel<<<dim3(W * 2, 4), 256, 0, stream>>>(
                x_embed, hbufs[child], cbufs[child], Wbig, bias_big,
                hbufs[outb], cbufs[outb], s);
        }
        child = outb;
    }

    final_kernel<<<128, 256, 0, stream>>>(init_emb, cbufs[child], hbufs[child],
                                          Woend, boend, out);
}